// Round 20
// baseline (463.624 us; speedup 1.0000x reference)
//
#include <hip/hip_runtime.h>

typedef _Float16 f16;
typedef f16 f16x2 __attribute__((ext_vector_type(2)));
typedef f16 f16x4 __attribute__((ext_vector_type(4)));
typedef f16 f16x8 __attribute__((ext_vector_type(8)));
typedef float f32x4 __attribute__((ext_vector_type(4)));

union v8split { f16x8 v8; f16x2 v2[4]; };

// ---------------- d_ws layout ----------------
#define WQF_OFF 0
#define WPF_OFF (768 * 256 * 2)                         // 393216
#define XW_OFF  (WPF_OFF + 256 * 256 * 2)               // 524288
#define O2_OFF  (XW_OFF + (size_t)2048 * 16384 * 2)     // +67108864
#define WS_NEED (O2_OFF + (size_t)2048 * 16384 * 2)     // 134742016

// LDS: bufX0 32KB | bufX1 32KB | qkv [64t][1536B] 96KB = 160KB exactly.
// Persistent block = one slab (8 windows), double-buffered xw prefetch.
#define QKV_LDS_OFF 65536
#define SMEM_TOTAL 163840

// fp32 -> fp16 weight conversion into FRAGMENT ORDER (r14-validated).
__global__ __launch_bounds__(256) void cvt_weights_frag_k(
    const float* __restrict__ wq, const float* __restrict__ wp,
    f16* __restrict__ wq_f, f16* __restrict__ wp_f) {
  int tid2 = blockIdx.x * 256 + threadIdx.x;  // 24576 (wq) + 8192 (wp)
  if (tid2 < 24576) {
    const int lane = tid2 & 63, kt = (tid2 >> 6) & 7, f0 = tid2 >> 9;
    const float* s = wq + (size_t)(f0 * 16 + (lane & 15)) * 256 + kt * 32 + (lane >> 4) * 8;
    f16* d = wq_f + (size_t)tid2 * 8;
#pragma unroll
    for (int e = 0; e < 8; ++e) d[e] = (f16)s[e];
  } else if (tid2 < 32768) {
    const int t2 = tid2 - 24576;
    const int lane = t2 & 63, kt = (t2 >> 6) & 7, f0 = t2 >> 9;
    const float* s = wp + (size_t)(f0 * 16 + (lane & 15)) * 256 + kt * 32 + (lane >> 4) * 8;
    f16* d = wp_f + (size_t)t2 * 8;
#pragma unroll
    for (int e = 0; e < 8; ++e) d[e] = (f16)s[e];
  }
}

// XOR-swizzled addr into a 64-row x 512B tile (xw / out2) — r10/r14-validated.
__device__ __forceinline__ char* xwp(char* s, int row, int colbyte) {
  return s + row * 512 + (colbyte ^ (((row ^ (row >> 3)) & 7) << 4));
}
// qkv tile [64 t][768 f], row stride 1536B — r10/r14-validated.
__device__ __forceinline__ char* qvp(char* s, int t, int fbyte) {
  return s + QKV_LDS_OFF + t * 1536 + (fbyte ^ ((t & 7) << 4));
}

// DPP quad_perm swaps: lane^1 and lane^2 (r11/r14-validated attention merge)
__device__ __forceinline__ float qswap1f(float v) {
  int x = __builtin_bit_cast(int, v);
  x = __builtin_amdgcn_update_dpp(0, x, 0xB1, 0xf, 0xf, true);  // [1,0,3,2]
  return __builtin_bit_cast(float, x);
}
__device__ __forceinline__ float qswap2f(float v) {
  int x = __builtin_bit_cast(int, v);
  x = __builtin_amdgcn_update_dpp(0, x, 0x4E, 0xf, 0xf, true);  // [2,3,0,1]
  return __builtin_bit_cast(float, x);
}

#if __has_builtin(__builtin_amdgcn_fdot2)
__device__ __forceinline__ float fdot2f(f16x2 a, f16x2 b, float c) {
  return __builtin_amdgcn_fdot2(a, b, c, false);
}
#else
__device__ __forceinline__ float fdot2f(f16x2 a, f16x2 b, float c) {
  return c + (float)a[0] * (float)b[0] + (float)a[1] * (float)b[1];
}
#endif

// ---- K1: gather/transpose x (fp32 strided, full 128B-line reads) -> xw_all
// (fp16, per-window contiguous 32KB, PRE-SWIZZLED to match xwp). r14 version.
__global__ __launch_bounds__(256) void gather_k(const float* __restrict__ x,
                                                f16* __restrict__ xw_all) {
  const int g = blockIdx.x >> 4, cb = blockIdx.x & 15;
  const int b = g >> 6, iw = (g >> 3) & 7, jw = g & 7;
  const int tid = threadIdx.x;
  const int c = cb * 16 + (tid >> 4), a = (tid >> 2) & 3, bb = tid & 3;
  const float* src = x + (size_t)b * 8388608 + (size_t)c * 32768 +
                     (iw * 4 + a) * 1024 + (jw * 4 + bb) * 32;
  const int t = c >> 2;
  const int c2b = (c & 3) * 128 + a * 32 + bb * 8;
  const int byt = t * 512 + (c2b ^ (((t ^ (t >> 3)) & 7) << 4));
  char* wbase = (char*)(xw_all + (size_t)(g << 3) * 16384) + byt;
#pragma unroll
  for (int kw = 0; kw < 8; ++kw) {
    float4 v = *(const float4*)(src + kw * 4);
    f16x4 h;
    h[0] = (f16)v.x; h[1] = (f16)v.y; h[2] = (f16)v.z; h[3] = (f16)v.w;
    *(f16x4*)(wbase + kw * 32768) = h;
  }
}

// ---- K2: PERSISTENT fused kernel (r19 schedule) with G1 split into two
// acc[3][2] passes: r19's acc[3][4]=48 + loop state overflowed the 64-VGPR
// budget (dynamic LDS hides the 1-block/CU limit from the allocator ->
// it targets 8 waves/EU) and spilled 693MB/426MB of scratch traffic.
// Peak live regs now ~54 < 64. af re-read in pass 2 hits L2 (weights hot).
__global__ __launch_bounds__(1024) void win_attn_k(
    const f16* __restrict__ xw_all, const f16* __restrict__ wq_f,
    const f16* __restrict__ wp_f, f16* __restrict__ o2T) {
  extern __shared__ char smem[];
  const int blk = blockIdx.x;
  const int tid = threadIdx.x, wv = tid >> 6, lane = tid & 63;
  const int lcol = lane & 15, lq = lane >> 4;
  char* buf0 = smem;
  char* buf1 = smem + 32768;

  // prefetch window w's pre-swizzled 32KB xw tile into buf (linear dest).
  auto PREF = [&](int w, char* buf) {
    const char* g = (const char*)(xw_all + (size_t)(blk * 8 + w) * 16384) + tid * 16;
    __builtin_amdgcn_global_load_lds(
        (const __attribute__((address_space(1))) void*)(g),
        (__attribute__((address_space(3))) void*)(buf + tid * 16), 16, 0, 0);
    __builtin_amdgcn_global_load_lds(
        (const __attribute__((address_space(1))) void*)(g + 16384),
        (__attribute__((address_space(3))) void*)(buf + tid * 16 + 16384), 16, 0, 0);
  };

  // GEMM1: wave = 48 f-cols; TWO passes over token tiles, acc[3][2] each.
  auto G1 = [&](char* buf) {
    const f16* wbase = wq_f + ((size_t)wv * 3 * 8) * 64 * 8 + lane * 8;
    const int fs = wv * 48;
#pragma unroll 1
    for (int half = 0; half < 2; ++half) {
      f32x4 acc[3][2] = {};
#pragma unroll
      for (int kt = 0; kt < 8; ++kt) {
        f16x8 bf[2];
#pragma unroll
        for (int nt = 0; nt < 2; ++nt)
          bf[nt] = *(const f16x8*)xwp(buf, (half * 2 + nt) * 16 + lcol, kt * 64 + lq * 16);
#pragma unroll
        for (int ms = 0; ms < 3; ++ms) {
          f16x8 af = *(const f16x8*)(wbase + (size_t)(ms * 8 + kt) * 512);
#pragma unroll
          for (int nt = 0; nt < 2; ++nt)
            acc[ms][nt] = __builtin_amdgcn_mfma_f32_16x16x32_f16(af, bf[nt], acc[ms][nt], 0, 0, 0);
        }
      }
      // D: col(lane&15)=token, row(lq*4+r)=feature -> f16x4 to qkv[t][f].
#pragma unroll
      for (int ms = 0; ms < 3; ++ms)
#pragma unroll
        for (int nt = 0; nt < 2; ++nt) {
          f16x4 hv;
          hv[0] = (f16)acc[ms][nt][0]; hv[1] = (f16)acc[ms][nt][1];
          hv[2] = (f16)acc[ms][nt][2]; hv[3] = (f16)acc[ms][nt][3];
          *(f16x4*)qvp(smem, (half * 2 + nt) * 16 + lcol, (fs + ms * 16 + lq * 4) * 2) = hv;
        }
    }
  };

  // Attention (r12/r14-validated): wave owns 4 tokens, lane=(tt<<4|h<<2|dq),
  // d-quarter per lane, DPP merges lane^1 then lane^2. out2 -> buf.
  auto ATTN = [&](char* buf) {
    const int tt = lane >> 4, h = (lane >> 2) & 3, dq = lane & 3;
    const int t = wv * 4 + tt;
    const int db = dq * 32;

    f16x2 q2[8];
#pragma unroll
    for (int j = 0; j < 2; ++j) {
      v8split u;
      u.v8 = *(const f16x8*)qvp(smem, t, h * 128 + db + j * 16);
      q2[j * 4 + 0] = u.v2[0]; q2[j * 4 + 1] = u.v2[1];
      q2[j * 4 + 2] = u.v2[2]; q2[j * 4 + 3] = u.v2[3];
    }
    float s[4];
#pragma unroll
    for (int g = 0; g < 4; ++g) {
      float a = 0.f;
#pragma unroll
      for (int j = 0; j < 2; ++j) {
        v8split u;
        u.v8 = *(const f16x8*)qvp(smem, t, 512 + g * 128 + db + j * 16);
        a = fdot2f(q2[j * 4 + 0], u.v2[0], a);
        a = fdot2f(q2[j * 4 + 1], u.v2[1], a);
        a = fdot2f(q2[j * 4 + 2], u.v2[2], a);
        a = fdot2f(q2[j * 4 + 3], u.v2[3], a);
      }
      s[g] = a;
    }
#pragma unroll
    for (int g = 0; g < 4; ++g) {
      s[g] += qswap1f(s[g]);   // merge dq^1
      s[g] += qswap2f(s[g]);   // merge dq^2 -> full 64-d dot on all 4 lanes
    }

    float mx = -1e30f;
#pragma unroll
    for (int g = 0; g < 4; ++g) {
      float v = fminf(fmaxf(s[g] * 0.125f, -10.f), 10.f);  // clip BEFORE softmax
      s[g] = v; mx = fmaxf(mx, v);
    }
    float sum = 0.f;
#pragma unroll
    for (int g = 0; g < 4; ++g) { s[g] = __expf(s[g] - mx); sum += s[g]; }
    float inv = 1.f / sum;
#pragma unroll
    for (int g = 0; g < 4; ++g) s[g] *= inv;

    float o[16] = {};
#pragma unroll
    for (int g = 0; g < 4; ++g) {
      float p = s[g];
#pragma unroll
      for (int j = 0; j < 2; ++j) {
        v8split u;
        u.v8 = *(const f16x8*)qvp(smem, t, 1024 + g * 128 + db + j * 16);
#pragma unroll
        for (int i = 0; i < 4; ++i) {
          o[j * 8 + 2 * i]     += p * (float)u.v2[i][0];
          o[j * 8 + 2 * i + 1] += p * (float)u.v2[i][1];
        }
      }
    }
    // out2 row = h*16 + t/4, colbyte = (t&3)*128 + dq*32 + j*16; into buf.
    const int row = h * 16 + (t >> 2);
    const int cb0 = (t & 3) * 128 + db;
#pragma unroll
    for (int j = 0; j < 2; ++j) {
      f16x8 ov;
      ov[0] = (f16)o[j * 8 + 0]; ov[1] = (f16)o[j * 8 + 1];
      ov[2] = (f16)o[j * 8 + 2]; ov[3] = (f16)o[j * 8 + 3];
      ov[4] = (f16)o[j * 8 + 4]; ov[5] = (f16)o[j * 8 + 5];
      ov[6] = (f16)o[j * 8 + 6]; ov[7] = (f16)o[j * 8 + 7];
      *(f16x8*)xwp(buf, row, cb0 + j * 16) = ov;
    }
  };

  // GEMM2 (r14-validated): wave = 16 c3-cols; writes o2T[wi].
  auto G2 = [&](char* buf, int w) {
    f32x4 acc2[4] = {};
    const int c3 = wv * 16 + lcol;
    const f16* bp = wp_f + ((size_t)wv * 8) * 64 * 8 + lane * 8;
#pragma unroll
    for (int kt = 0; kt < 8; ++kt) {
      f16x8 bfr = *(const f16x8*)(bp + (size_t)kt * 512);
#pragma unroll
      for (int mt = 0; mt < 4; ++mt) {
        f16x8 afr = *(const f16x8*)xwp(buf, mt * 16 + lcol, kt * 64 + lq * 16);
        acc2[mt] = __builtin_amdgcn_mfma_f32_16x16x32_f16(afr, bfr, acc2[mt], 0, 0, 0);
      }
    }
    f16* ob = o2T + (size_t)(blk * 8 + w) * 16384;
#pragma unroll
    for (int mt = 0; mt < 4; ++mt) {
      f16x4 hv;
      hv[0] = (f16)acc2[mt][0]; hv[1] = (f16)acc2[mt][1];
      hv[2] = (f16)acc2[mt][2]; hv[3] = (f16)acc2[mt][3];
      *(f16x4*)(ob + c3 * 64 + mt * 16 + lq * 4) = hv;
    }
  };

  // ---- persistent schedule: 2 syncthreads per window (r19 hazard analysis
  // unchanged: PREF(w+1) after sync[A] is safe; sync[B] drains prefetch). ----
  PREF(0, buf0);
  __syncthreads();
#pragma unroll 1
  for (int w = 0; w < 8; ++w) {
    char* cur = (w & 1) ? buf1 : buf0;
    char* nxt = (w & 1) ? buf0 : buf1;
    G1(cur);
    __syncthreads();            // sync[A]: qkv ready
    if (w < 7) PREF(w + 1, nxt);
    ATTN(cur);
    __syncthreads();            // sync[B]: out2 ready + prefetch drained
    G2(cur, w);                 // no barrier before next G1 (disjoint LDS)
  }
}

// ---- K3: scatter o2T (fp16, L3-hot) -> out (fp32, full 128B-line writes).
__global__ __launch_bounds__(256) void scatter_k(const f16* __restrict__ o2T,
                                                 float* __restrict__ out) {
  const int g = blockIdx.x >> 4, cb = blockIdx.x & 15;
  const int b = g >> 6, iw = (g >> 3) & 7, jw = g & 7;
  const int tid = threadIdx.x;
  const int c3 = cb * 16 + (tid >> 4), a = (tid >> 2) & 3, bb = tid & 3;
  const f16* rbase = o2T + (size_t)(g << 3) * 16384 + c3 * 64 + a * 16 + bb * 4;
  float* dst = out + (size_t)b * 8388608 + (size_t)c3 * 32768 +
               (iw * 4 + a) * 1024 + (jw * 4 + bb) * 32;
#pragma unroll
  for (int kw = 0; kw < 8; ++kw) {
    f16x4 h = *(const f16x4*)(rbase + kw * 16384);
    float4 v;
    v.x = (float)h[0]; v.y = (float)h[1]; v.z = (float)h[2]; v.w = (float)h[3];
    *(float4*)(dst + kw * 4) = v;
  }
}

extern "C" void kernel_launch(void* const* d_in, const int* in_sizes, int n_in,
                              void* d_out, int out_size, void* d_ws, size_t ws_size,
                              hipStream_t stream) {
  const float* x = (const float*)d_in[0];
  const float* wq = (const float*)d_in[1];
  const float* wp = (const float*)d_in[2];
  float* out = (float*)d_out;
  char* ws = (char*)d_ws;
  f16* wq_f = (f16*)(ws + WQF_OFF);
  f16* wp_f = (f16*)(ws + WPF_OFF);
  f16* xw_all = (f16*)(ws + XW_OFF);
  f16* o2T = (f16*)(ws + O2_OFF);

  (void)hipFuncSetAttribute((const void*)win_attn_k,
                            hipFuncAttributeMaxDynamicSharedMemorySize, SMEM_TOTAL);

  cvt_weights_frag_k<<<128, 256, 0, stream>>>(wq, wp, wq_f, wp_f);
  gather_k<<<4096, 256, 0, stream>>>(x, xw_all);
  win_attn_k<<<256, 1024, SMEM_TOTAL, stream>>>(xw_all, wq_f, wp_f, o2T);
  scatter_k<<<4096, 256, 0, stream>>>(o2T, out);
}

// Round 21
// 224.142 us; speedup vs baseline: 2.0684x; 2.0684x over previous
//
#include <hip/hip_runtime.h>

typedef _Float16 f16;
typedef f16 f16x2 __attribute__((ext_vector_type(2)));
typedef f16 f16x4 __attribute__((ext_vector_type(4)));
typedef f16 f16x8 __attribute__((ext_vector_type(8)));
typedef float f32x4 __attribute__((ext_vector_type(4)));

union v8split { f16x8 v8; f16x2 v2[4]; };

// ---------------- d_ws layout ----------------
// wq_f: fragment-ordered w_qkv (48 fblk x 8 kt x 64 lane x 8 halfs)
// wp_f: fragment-ordered w_proj (16 fblk x 8 kt x 64 lane x 8 halfs)
#define WQF_OFF 0
#define WPF_OFF (768 * 256 * 2)                         // 393216
#define XW_OFF  (WPF_OFF + 256 * 256 * 2)               // 524288
#define O2_OFF  (XW_OFF + (size_t)2048 * 16384 * 2)     // +67108864
#define WS_NEED (O2_OFF + (size_t)2048 * 16384 * 2)     // 134742016

// LDS: bufX (xw/out2) 32KB | qkv [64t][1536B] 96KB = 128KB -> 1 block/CU,
// 1024 threads = 16 waves = 4 waves/SIMD (r12/r14-validated structure).
#define QKV_LDS_OFF 32768
#define SMEM_TOTAL 131072

// fp32 -> fp16 weight conversion into FRAGMENT ORDER: the GEMM fragment
// load for (fblock, kt) at lane l is a contiguous 16B at
// frag[((fblock*8 + kt)*64 + l)*8]. r13 diagnosis: row-major addressing made
// every fragment load touch 16 scattered half-used lines (lcol stride 512B).
__global__ __launch_bounds__(256) void cvt_weights_frag_k(
    const float* __restrict__ wq, const float* __restrict__ wp,
    f16* __restrict__ wq_f, f16* __restrict__ wp_f) {
  int tid2 = blockIdx.x * 256 + threadIdx.x;  // 24576 (wq) + 8192 (wp)
  if (tid2 < 24576) {
    const int lane = tid2 & 63, kt = (tid2 >> 6) & 7, f0 = tid2 >> 9;
    const float* s = wq + (size_t)(f0 * 16 + (lane & 15)) * 256 + kt * 32 + (lane >> 4) * 8;
    f16* d = wq_f + (size_t)tid2 * 8;
#pragma unroll
    for (int e = 0; e < 8; ++e) d[e] = (f16)s[e];
  } else if (tid2 < 32768) {
    const int t2 = tid2 - 24576;
    const int lane = t2 & 63, kt = (t2 >> 6) & 7, f0 = t2 >> 9;
    const float* s = wp + (size_t)(f0 * 16 + (lane & 15)) * 256 + kt * 32 + (lane >> 4) * 8;
    f16* d = wp_f + (size_t)t2 * 8;
#pragma unroll
    for (int e = 0; e < 8; ++e) d[e] = (f16)s[e];
  }
}

// XOR-swizzled addr into a 64-row x 512B tile (xw / out2) — r10/r12-validated.
__device__ __forceinline__ char* xwp(char* s, int row, int colbyte) {
  return s + row * 512 + (colbyte ^ (((row ^ (row >> 3)) & 7) << 4));
}
// qkv tile [64 t][768 f], row stride 1536B — r10/r12-validated.
__device__ __forceinline__ char* qvp(char* s, int t, int fbyte) {
  return s + QKV_LDS_OFF + t * 1536 + (fbyte ^ ((t & 7) << 4));
}

// DPP quad_perm swaps: lane^1 and lane^2 (r11/r12-validated attention merge)
__device__ __forceinline__ float qswap1f(float v) {
  int x = __builtin_bit_cast(int, v);
  x = __builtin_amdgcn_update_dpp(0, x, 0xB1, 0xf, 0xf, true);  // [1,0,3,2]
  return __builtin_bit_cast(float, x);
}
__device__ __forceinline__ float qswap2f(float v) {
  int x = __builtin_bit_cast(int, v);
  x = __builtin_amdgcn_update_dpp(0, x, 0x4E, 0xf, 0xf, true);  // [2,3,0,1]
  return __builtin_bit_cast(float, x);
}

#if __has_builtin(__builtin_amdgcn_fdot2)
__device__ __forceinline__ float fdot2f(f16x2 a, f16x2 b, float c) {
  return __builtin_amdgcn_fdot2(a, b, c, false);
}
#else
__device__ __forceinline__ float fdot2f(f16x2 a, f16x2 b, float c) {
  return c + (float)a[0] * (float)b[0] + (float)a[1] * (float)b[1];
}
#endif

// ---- K1: gather/transpose x (fp32 strided, full 128B-line reads) -> xw_all
// (fp16, per-window contiguous 32KB, PRE-SWIZZLED to match xwp). r10 version.
__global__ __launch_bounds__(256) void gather_k(const float* __restrict__ x,
                                                f16* __restrict__ xw_all) {
  const int g = blockIdx.x >> 4, cb = blockIdx.x & 15;
  const int b = g >> 6, iw = (g >> 3) & 7, jw = g & 7;
  const int tid = threadIdx.x;
  const int c = cb * 16 + (tid >> 4), a = (tid >> 2) & 3, bb = tid & 3;
  const float* src = x + (size_t)b * 8388608 + (size_t)c * 32768 +
                     (iw * 4 + a) * 1024 + (jw * 4 + bb) * 32;
  const int t = c >> 2;
  const int c2b = (c & 3) * 128 + a * 32 + bb * 8;
  const int byt = t * 512 + (c2b ^ (((t ^ (t >> 3)) & 7) << 4));
  char* wbase = (char*)(xw_all + (size_t)(g << 3) * 16384) + byt;
#pragma unroll
  for (int kw = 0; kw < 8; ++kw) {
    float4 v = *(const float4*)(src + kw * 4);
    f16x4 h;
    h[0] = (f16)v.x; h[1] = (f16)v.y; h[2] = (f16)v.z; h[3] = (f16)v.w;
    *(f16x4*)(wbase + kw * 32768) = h;
  }
}

// ---- K2: fused per-window kernel (r12 structure, fragment-order weights).
__global__ __launch_bounds__(1024) void win_attn_k(
    const f16* __restrict__ xw_all, const f16* __restrict__ wq_f,
    const f16* __restrict__ wp_f, f16* __restrict__ o2T) {
  extern __shared__ char smem[];
  const int wi = blockIdx.x;
  const int tid = threadIdx.x, wv = tid >> 6, lane = tid & 63;
  const int lcol = lane & 15, lq = lane >> 4;

  // Phase 1: 32KB pre-swizzled xw -> LDS (linear dest, 2x16B per thread).
  {
    const char* g = (const char*)(xw_all + (size_t)wi * 16384) + tid * 16;
    __builtin_amdgcn_global_load_lds(
        (const __attribute__((address_space(1))) void*)(g),
        (__attribute__((address_space(3))) void*)(smem + tid * 16), 16, 0, 0);
    __builtin_amdgcn_global_load_lds(
        (const __attribute__((address_space(1))) void*)(g + 16384),
        (__attribute__((address_space(3))) void*)(smem + tid * 16 + 16384), 16, 0, 0);
  }
  __syncthreads();

  // Phase 2: GEMM1 qkv[64t x 768f]. Wave = 48 f-cols (fblocks wv*3..wv*3+2),
  // acc[3][4]; af loads per-wave contiguous 1KB from wq_f.
  {
    f32x4 acc[3][4] = {};
    const f16* wbase = wq_f + ((size_t)wv * 3 * 8 + 0) * 64 * 8 + lane * 8;
#pragma unroll
    for (int kt = 0; kt < 8; ++kt) {
      f16x8 bf[4];
#pragma unroll
      for (int nt = 0; nt < 4; ++nt)
        bf[nt] = *(const f16x8*)xwp(smem, nt * 16 + lcol, kt * 64 + lq * 16);
#pragma unroll
      for (int ms = 0; ms < 3; ++ms) {
        f16x8 af = *(const f16x8*)(wbase + (size_t)(ms * 8 + kt) * 512);
#pragma unroll
        for (int nt = 0; nt < 4; ++nt)
          acc[ms][nt] = __builtin_amdgcn_mfma_f32_16x16x32_f16(af, bf[nt], acc[ms][nt], 0, 0, 0);
      }
    }
    // D: col(lane&15)=token, row(lq*4+r)=feature -> f16x4 to qkv[t][f].
    const int fs = wv * 48;
#pragma unroll
    for (int ms = 0; ms < 3; ++ms)
#pragma unroll
      for (int nt = 0; nt < 4; ++nt) {
        f16x4 hv;
        hv[0] = (f16)acc[ms][nt][0]; hv[1] = (f16)acc[ms][nt][1];
        hv[2] = (f16)acc[ms][nt][2]; hv[3] = (f16)acc[ms][nt][3];
        *(f16x4*)qvp(smem, nt * 16 + lcol, (fs + ms * 16 + lq * 4) * 2) = hv;
      }
  }
  __syncthreads();

  // Phase 3: per-token attention (r12-validated). Wave owns 4 tokens;
  // lane = (tt<<4|h<<2|dq); d-quarter per lane; DPP merges lane^1, lane^2.
  {
    const int tt = lane >> 4, h = (lane >> 2) & 3, dq = lane & 3;
    const int t = wv * 4 + tt;
    const int db = dq * 32;

    f16x2 q2[8];
#pragma unroll
    for (int j = 0; j < 2; ++j) {
      v8split u;
      u.v8 = *(const f16x8*)qvp(smem, t, h * 128 + db + j * 16);
      q2[j * 4 + 0] = u.v2[0]; q2[j * 4 + 1] = u.v2[1];
      q2[j * 4 + 2] = u.v2[2]; q2[j * 4 + 3] = u.v2[3];
    }
    float s[4];
#pragma unroll
    for (int g = 0; g < 4; ++g) {
      float a = 0.f;
#pragma unroll
      for (int j = 0; j < 2; ++j) {
        v8split u;
        u.v8 = *(const f16x8*)qvp(smem, t, 512 + g * 128 + db + j * 16);
        a = fdot2f(q2[j * 4 + 0], u.v2[0], a);
        a = fdot2f(q2[j * 4 + 1], u.v2[1], a);
        a = fdot2f(q2[j * 4 + 2], u.v2[2], a);
        a = fdot2f(q2[j * 4 + 3], u.v2[3], a);
      }
      s[g] = a;
    }
#pragma unroll
    for (int g = 0; g < 4; ++g) {
      s[g] += qswap1f(s[g]);   // merge dq^1
      s[g] += qswap2f(s[g]);   // merge dq^2 -> full 64-d dot on all 4 lanes
    }

    float mx = -1e30f;
#pragma unroll
    for (int g = 0; g < 4; ++g) {
      float v = fminf(fmaxf(s[g] * 0.125f, -10.f), 10.f);  // clip BEFORE softmax
      s[g] = v; mx = fmaxf(mx, v);
    }
    float sum = 0.f;
#pragma unroll
    for (int g = 0; g < 4; ++g) { s[g] = __expf(s[g] - mx); sum += s[g]; }
    float inv = 1.f / sum;
#pragma unroll
    for (int g = 0; g < 4; ++g) s[g] *= inv;

    float o[16] = {};
#pragma unroll
    for (int g = 0; g < 4; ++g) {
      float p = s[g];
#pragma unroll
      for (int j = 0; j < 2; ++j) {
        v8split u;
        u.v8 = *(const f16x8*)qvp(smem, t, 1024 + g * 128 + db + j * 16);
#pragma unroll
        for (int i = 0; i < 4; ++i) {
          o[j * 8 + 2 * i]     += p * (float)u.v2[i][0];
          o[j * 8 + 2 * i + 1] += p * (float)u.v2[i][1];
        }
      }
    }
    // out2 row = h*16 + t/4, colbyte = (t&3)*128 + dq*32 + j*16; reuse bufX.
    const int row = h * 16 + (t >> 2);
    const int cb0 = (t & 3) * 128 + db;
#pragma unroll
    for (int j = 0; j < 2; ++j) {
      f16x8 ov;
      ov[0] = (f16)o[j * 8 + 0]; ov[1] = (f16)o[j * 8 + 1];
      ov[2] = (f16)o[j * 8 + 2]; ov[3] = (f16)o[j * 8 + 3];
      ov[4] = (f16)o[j * 8 + 4]; ov[5] = (f16)o[j * 8 + 5];
      ov[6] = (f16)o[j * 8 + 6]; ov[7] = (f16)o[j * 8 + 7];
      *(f16x8*)xwp(smem, row, cb0 + j * 16) = ov;
    }
  }
  __syncthreads();

  // Phase 4: GEMM2. Wave = 16 c3-cols (fblock = wv); bfr per-wave contiguous.
  {
    f32x4 acc2[4] = {};
    const int c3 = wv * 16 + lcol;
    const f16* bp = wp_f + ((size_t)wv * 8) * 64 * 8 + lane * 8;
#pragma unroll
    for (int kt = 0; kt < 8; ++kt) {
      f16x8 bfr = *(const f16x8*)(bp + (size_t)kt * 512);
#pragma unroll
      for (int mt = 0; mt < 4; ++mt) {
        f16x8 afr = *(const f16x8*)xwp(smem, mt * 16 + lcol, kt * 64 + lq * 16);
        acc2[mt] = __builtin_amdgcn_mfma_f32_16x16x32_f16(afr, bfr, acc2[mt], 0, 0, 0);
      }
    }
    // D: col = c3, row = token t2 = mt*16 + lq*4 + r -> o2T[c3][t2].
    f16* ob = o2T + (size_t)wi * 16384;
#pragma unroll
    for (int mt = 0; mt < 4; ++mt) {
      f16x4 hv;
      hv[0] = (f16)acc2[mt][0]; hv[1] = (f16)acc2[mt][1];
      hv[2] = (f16)acc2[mt][2]; hv[3] = (f16)acc2[mt][3];
      *(f16x4*)(ob + c3 * 64 + mt * 16 + lq * 4) = hv;
    }
  }
}

// ---- K3: scatter o2T (fp16, L3-hot) -> out (fp32, full 128B-line writes).
__global__ __launch_bounds__(256) void scatter_k(const f16* __restrict__ o2T,
                                                 float* __restrict__ out) {
  const int g = blockIdx.x >> 4, cb = blockIdx.x & 15;
  const int b = g >> 6, iw = (g >> 3) & 7, jw = g & 7;
  const int tid = threadIdx.x;
  const int c3 = cb * 16 + (tid >> 4), a = (tid >> 2) & 3, bb = tid & 3;
  const f16* rbase = o2T + (size_t)(g << 3) * 16384 + c3 * 64 + a * 16 + bb * 4;
  float* dst = out + (size_t)b * 8388608 + (size_t)c3 * 32768 +
               (iw * 4 + a) * 1024 + (jw * 4 + bb) * 32;
#pragma unroll
  for (int kw = 0; kw < 8; ++kw) {
    f16x4 h = *(const f16x4*)(rbase + kw * 16384);
    float4 v;
    v.x = (float)h[0]; v.y = (float)h[1]; v.z = (float)h[2]; v.w = (float)h[3];
    *(float4*)(dst + kw * 4) = v;
  }
}

extern "C" void kernel_launch(void* const* d_in, const int* in_sizes, int n_in,
                              void* d_out, int out_size, void* d_ws, size_t ws_size,
                              hipStream_t stream) {
  const float* x = (const float*)d_in[0];
  const float* wq = (const float*)d_in[1];
  const float* wp = (const float*)d_in[2];
  float* out = (float*)d_out;
  char* ws = (char*)d_ws;
  f16* wq_f = (f16*)(ws + WQF_OFF);
  f16* wp_f = (f16*)(ws + WPF_OFF);
  f16* xw_all = (f16*)(ws + XW_OFF);
  f16* o2T = (f16*)(ws + O2_OFF);

  (void)hipFuncSetAttribute((const void*)win_attn_k,
                            hipFuncAttributeMaxDynamicSharedMemorySize, SMEM_TOTAL);

  cvt_weights_frag_k<<<128, 256, 0, stream>>>(wq, wp, wq_f, wp_f);
  gather_k<<<4096, 256, 0, stream>>>(x, xw_all);
  win_attn_k<<<2048, 1024, SMEM_TOTAL, stream>>>(xw_all, wq_f, wp_f, o2T);
  scatter_k<<<4096, 256, 0, stream>>>(o2T, out);
}